// Round 12
// baseline (146.246 us; speedup 1.0000x reference)
//
#include <hip/hip_runtime.h>
#include <stdint.h>
#include <stddef.h>

// ---------------- problem constants ----------------
// B=2048, F0=39, D=16, layers 128/128/128, xk halves to 64 after each layer.
// Factored form: y_h[s,d] = sum_k W[h,k,s]*xk[b,k,d] (MFMA: A=W static, B=xk
// h-invariant -> register-cached per layer); z[b,s,d] = sum_h x0[b,h,d]*y_h[s,d].
// R12 = R11 (256 x 1024, 1 block/CU, 4 waves/SIMD — verified 38% occ, no
// spill) + two latency fixes:
//  (a) W prefetch depth 2 (Wc/Wn/Wn2): first use waits vmcnt(2), ~2 steps of
//      L2 latency covered (R11's dist-1 left ~1 L2 round-trip exposed);
//  (b) X0TS 44->45: xs bank = 13*l16%32 -> 16 distinct banks (R11's 44 gave
//      12*l16%32 = 8 banks, 2-way every read -> 4.69M conflict cycles);
//      plus dist-1 xs prefetch.
#define F0N  39
#define SN   128
#define NB   8             // batches per block
#define X0TS 45            // f32 stride of X0T row (b,d): odd*... -> conflict-free
#define XKTS 72            // u16 stride of XKT row (b,d): 64+8 pad, 16B-aligned
#define WBLK 8192          // u16 per (L,h) W block: 8 s-tiles x 2 chunks x 512
#define NHB2 234           // 3*39*2 prepass blocks (one per (L,h,k-half))

typedef __attribute__((ext_vector_type(8))) short short8;   // MFMA A/B operand
typedef __attribute__((ext_vector_type(4))) float floatx4;  // MFMA accumulator

__device__ __forceinline__ uint16_t f2bf(float f) {         // RNE f32->bf16
  uint32_t u = __float_as_uint(f);
  u += 0x7fffu + ((u >> 16) & 1u);
  return (uint16_t)(u >> 16);
}

// ---------------- pre-pass: W fp32 -> bf16 A-fragment blocks (R11-verified) ----------------
// One block per (L,h,ch). Layout: wt[(L*39+h)*WBLK + (st*2+ch)*512 + lane*8 + j],
// value = W[h][k=ch*32+quad*8+j][s=st*16+l16].
__global__ __launch_bounds__(256) void cin_prepass(
    const float* __restrict__ w0, const float* __restrict__ w1,
    const float* __restrict__ w2, uint16_t* __restrict__ wt) {
  __shared__ float T[32 * 132];               // [k_local][s], +4 pad floats/row
  const int bc = blockIdx.x;                  // 0..233
  const int ch = bc & 1;
  const int lh = bc >> 1;                     // 0..116
  const int L = lh / F0N;
  const int h = lh - L * F0N;
  const float* W = (L == 0) ? w0 : ((L == 1) ? w1 : w2);
  const int fk = (L == 0) ? 39 : 64;
  const int tid = threadIdx.x;

  for (int e = tid; e < 4096; e += 256) {     // coalesced fp32 read
    int kc = e >> 7, s = e & 127;
    int k = ch * 32 + kc;
    T[kc * 132 + s] = (k < fk) ? W[(h * fk + k) * SN + s] : 0.0f;
  }
  __syncthreads();
  uint32_t* dst = (uint32_t*)(wt + (size_t)lh * WBLK);
  for (int i = tid; i < 2048; i += 256) {     // coalesced u32 writes, frag order
    int st = i >> 8, w = i & 255;
    int ln = w >> 2, jp = w & 3;
    int quad = ln >> 4, l16 = ln & 15;
    int k0 = quad * 8 + jp * 2;               // local k within this half
    int s = st * 16 + l16;
    dst[(size_t)(st * 2 + ch) * 256 + w] =
        (uint32_t)f2bf(T[k0 * 132 + s]) | ((uint32_t)f2bf(T[(k0 + 1) * 132 + s]) << 16);
  }
}

// ---------------- fused main kernel ----------------
// 256 blocks x 1024 threads (16 waves), 1 block/CU, 4 waves/SIMD.
// Block owns NB=8 batches x full s. Wave (st,bg): s-tile [st*16,st*16+16) x
// batches [bg*4,bg*4+4). Per layer: Bf register-cached; per h: 2 coalesced
// global W-frag loads (depth-2 register prefetch, no barriers in h-loop),
// 4 conflict-free x0 ds_reads (dist-1 prefetch), 8 MFMA + 16 fmac. h runs to
// 40; h=39 has xs=0 (X0T pad) so its W (clamped addr) contributes 0.
// D-layout: D[s=st*16+quad*4+r][d=l16]; sum_d = shfl_xor over l16 bits.
__global__ __launch_bounds__(1024) void cin_main(
    const float* __restrict__ x,       // (2048, 39, 16) fp32
    const float* __restrict__ bias0, const float* __restrict__ bias1,
    const float* __restrict__ bias2,
    const uint16_t* __restrict__ wt,   // A-frag bf16 weights (d_ws)
    float* __restrict__ out) {         // (2048, 256) fp32

  __shared__ float    X0T[NB * 16 * X0TS];                // x0[b][d][h] f32, 23040 B
  __shared__ __align__(16) uint16_t XKT[NB * 16 * XKTS];  // xk[b][d][k] bf16, 18432 B

  const int tid  = threadIdx.x;
  const int lane = tid & 63;
  const int wave = tid >> 6;           // 0..15
  const int st   = wave >> 1;          // s-tile 0..7
  const int bg   = wave & 1;           // batch group 0..1
  const int l16  = lane & 15;          // = d (output col)
  const int quad = lane >> 4;
  const int bbase = blockIdx.x * NB;

  // zero X0T (h-pad 39..44 must be 0 -> xs=0 at h=39/40) and XKT (k-pad for L0)
  {
    float* p = X0T;                    // 5760 floats
#pragma unroll
    for (int i = 0; i < 6; i++) { int e = tid + 1024 * i; if (e < 5760) p[e] = 0.f; }
    uint32_t* q = (uint32_t*)XKT;      // 4608 dwords
#pragma unroll
    for (int i = 0; i < 5; i++) { int e = tid + 1024 * i; if (e < 4608) q[e] = 0u; }
  }
  __syncthreads();

  // fill X0T[b][d][h] = x[bbase+b][h][d]  (coalesced read, LDS transpose-scatter)
#pragma unroll
  for (int it = 0; it < 5; ++it) {
    int e = tid + it * 1024;           // e = (b*39 + h)*16 + d, total 4992
    if (e < NB * F0N * 16) {
      float v = x[(size_t)bbase * (F0N * 16) + e];
      int d = e & 15, p = e >> 4;
      int b = p / F0N, h = p - b * F0N;
      X0T[(b * 16 + d) * X0TS + h] = v;
    }
  }
  __syncthreads();

  // build layer-0 XKT[b][d][k] = bf16(x0[b][k][d]) for k<39, 0 for k in [39,64)
  if (tid < 512) {
    int b = tid >> 6, d = (tid >> 2) & 15, kg = tid & 3;
    const float* src = &X0T[(b * 16 + d) * X0TS];
    uint32_t* drow = (uint32_t*)&XKT[(b * 16 + d) * XKTS + kg * 16];
#pragma unroll
    for (int i2 = 0; i2 < 8; i2++) {
      int k0 = kg * 16 + i2 * 2;
      uint32_t lo = (k0 < 39)     ? (uint32_t)f2bf(src[k0])     : 0u;
      uint32_t hi = (k0 + 1 < 39) ? (uint32_t)f2bf(src[k0 + 1]) : 0u;
      drow[i2] = lo | (hi << 16);
    }
  }
  __syncthreads();   // XKT build visible for Bf loads

  // per-wave global W base (u16 units) — bg-pair waves share addresses (L1)
  const uint16_t* wlane = wt + st * 1024 + (size_t)lane * 8;

  // W block address for global step g in [0,120): L=g/40, h=min(g%40,38)
  auto wstep = [&](int g) -> const uint16_t* {
    int Lp = (g * 205) >> 13;          // g/40 for g<120
    int hp = g - Lp * 40;
    if (hp > 38) hp = 38;              // h=39 consumed with xs=0: content unused
    return wlane + (size_t)(Lp * F0N + hp) * WBLK;
  };

  // seed depth-2 prefetch: g=0, g=1
  short8 Wc0 = *(const short8*)wstep(0);
  short8 Wc1 = *(const short8*)(wstep(0) + 512);
  short8 Wn0 = *(const short8*)wstep(1);
  short8 Wn1 = *(const short8*)(wstep(1) + 512);

#pragma unroll 1
  for (int L = 0; L < 3; ++L) {
    // register-cache B-fragments (h-invariant within layer); b = bg*4 + bi
    short8 Bf0[4], Bf1[4];
#pragma unroll
    for (int bi = 0; bi < 4; ++bi) {
      const uint16_t* r = XKT + ((bg * 4 + bi) * 16 + l16) * XKTS + quad * 8;
      Bf0[bi] = *(const short8*)r;          // k 0..31 chunk
      Bf1[bi] = *(const short8*)(r + 32);   // k 32..63 chunk
    }
    const float* bp = (L == 0) ? bias0 : ((L == 1) ? bias1 : bias2);
    float bvr[4];
#pragma unroll
    for (int r = 0; r < 4; ++r) bvr[r] = bp[st * 16 + quad * 4 + r];

    floatx4 z[4] = {};
    const floatx4 zero4 = {0.f, 0.f, 0.f, 0.f};

    // seed xs for h=0
    float xsC[4];
#pragma unroll
    for (int bi = 0; bi < 4; ++bi)
      xsC[bi] = X0T[((bg * 4 + bi) * 16 + l16) * X0TS + 0];

#pragma unroll 1
    for (int h = 0; h < 40; ++h) {
      // depth-2 W prefetch: load for step g+2 (clamped); first use of Wc
      // waits vmcnt(2) -> ~2 steps of L2 latency covered
      short8 W20, W21;
      {
        int gp = L * 40 + h + 2;
        if (gp > 119) gp = 119;
        const uint16_t* wl = wstep(gp);
        W20 = *(const short8*)wl;
        W21 = *(const short8*)(wl + 512);
      }
      // dist-1 xs prefetch (h+1 <= 40 < X0TS, zero-padded)
      float xsN[4];
#pragma unroll
      for (int bi = 0; bi < 4; ++bi)
        xsN[bi] = X0T[((bg * 4 + bi) * 16 + l16) * X0TS + h + 1];

#pragma unroll
      for (int bi = 0; bi < 4; ++bi) {
        floatx4 y = __builtin_amdgcn_mfma_f32_16x16x32_bf16(Wc0, Bf0[bi], zero4, 0, 0, 0);
        y = __builtin_amdgcn_mfma_f32_16x16x32_bf16(Wc1, Bf1[bi], y, 0, 0, 0);
#pragma unroll
        for (int r = 0; r < 4; ++r) z[bi][r] += xsC[bi] * y[r];
      }
      Wc0 = Wn0; Wc1 = Wn1;
      Wn0 = W20; Wn1 = W21;
#pragma unroll
      for (int bi = 0; bi < 4; ++bi) xsC[bi] = xsN[bi];
    }

    // ---- epilogue: bias+relu; xk handoff; sum_d (over l16) -> out ----
#pragma unroll
    for (int bi = 0; bi < 4; ++bi) {
      const int b = bg * 4 + bi;
#pragma unroll
      for (int r = 0; r < 4; ++r) {
        float t = fmaxf(z[bi][r] + bvr[r], 0.f);
        if (L < 2 && st < 4)               // xk = relu(z)[:, :64]; k = s < 64
          XKT[(b * 16 + l16) * XKTS + st * 16 + quad * 4 + r] = f2bf(t);
        float s4 = t;                       // reduce over d = l16 (bits 0..3)
        s4 += __shfl_xor(s4, 1);
        s4 += __shfl_xor(s4, 2);
        s4 += __shfl_xor(s4, 4);
        s4 += __shfl_xor(s4, 8);
        if (l16 == 0) {
          int s = st * 16 + quad * 4 + r;
          // concat: L0 s64:128 -> 0:64 ; L1 s64:128 -> 64:128 ; L2 s -> 128:256
          if (L == 2)       out[(size_t)(bbase + b) * 256 + 128 + s] = s4;
          else if (s >= 64) out[(size_t)(bbase + b) * 256 + L * 64 + (s - 64)] = s4;
        }
      }
    }
    if (L < 2) __syncthreads();   // handoff writes visible before next-layer Bf loads
  }
}

extern "C" void kernel_launch(void* const* d_in, const int* in_sizes, int n_in,
                              void* d_out, int out_size, void* d_ws, size_t ws_size,
                              hipStream_t stream) {
  (void)in_sizes; (void)n_in; (void)out_size; (void)ws_size;
  const float* x  = (const float*)d_in[0];
  const float* w0 = (const float*)d_in[1];
  const float* b0 = (const float*)d_in[2];
  const float* w1 = (const float*)d_in[3];
  const float* b1 = (const float*)d_in[4];
  const float* w2 = (const float*)d_in[5];
  const float* b2 = (const float*)d_in[6];
  uint16_t* wt    = (uint16_t*)d_ws;   // 117 * 8192 * 2 = 1,916,928 B

  cin_prepass<<<NHB2, 256, 0, stream>>>(w0, w1, w2, wt);
  cin_main<<<256, 1024, 0, stream>>>(x, b0, b1, b2, wt, (float*)d_out);
}

// Round 14
// 136.839 us; speedup vs baseline: 1.0687x; 1.0687x over previous
//
#include <hip/hip_runtime.h>
#include <stdint.h>
#include <stddef.h>

// ---------------- problem constants ----------------
// B=2048, F0=39, D=16, layers 128/128/128, xk halves to 64 after each layer.
// Factored form: y_h[s,d] = sum_k W[h,k,s]*xk[b,k,d] (MFMA: A=W static, B=xk
// h-invariant -> register-cached per layer); z[b,s,d] = sum_h x0[b,h,d]*y_h[s,d].
// R14 = R11's exact loop structure (dist-1 W rotation, verified-correct) +
// R12's two verified fixes only: X0TS=45 (xs bank = 13*l16%32 -> 16 distinct
// banks; R11's 44 gave 8 banks 2-way -> 4.69M conflict cycles, R12 measured
// 0.69M) and dist-1 xs prefetch. The R12 third W buffer (AGPR shuffling,
// +10us) and R13 use-then-reload (failed correctness, bug not isolated) are
// both reverted.
#define F0N  39
#define SN   128
#define NB   8             // batches per block
#define X0TS 45            // f32 stride of X0T row (b,d): conflict-free scalar xs
#define XKTS 72            // u16 stride of XKT row (b,d): 64+8 pad, 16B-aligned
#define WBLK 8192          // u16 per (L,h) W block: 8 s-tiles x 2 chunks x 512
#define NHB2 234           // 3*39*2 prepass blocks (one per (L,h,k-half))

typedef __attribute__((ext_vector_type(8))) short short8;   // MFMA A/B operand
typedef __attribute__((ext_vector_type(4))) float floatx4;  // MFMA accumulator

__device__ __forceinline__ uint16_t f2bf(float f) {         // RNE f32->bf16
  uint32_t u = __float_as_uint(f);
  u += 0x7fffu + ((u >> 16) & 1u);
  return (uint16_t)(u >> 16);
}

// ---------------- pre-pass: W fp32 -> bf16 A-fragment blocks (R11-verified) ----------------
// One block per (L,h,ch). Layout: wt[(L*39+h)*WBLK + (st*2+ch)*512 + lane*8 + j],
// value = W[h][k=ch*32+quad*8+j][s=st*16+l16].
__global__ __launch_bounds__(256) void cin_prepass(
    const float* __restrict__ w0, const float* __restrict__ w1,
    const float* __restrict__ w2, uint16_t* __restrict__ wt) {
  __shared__ float T[32 * 132];               // [k_local][s], +4 pad floats/row
  const int bc = blockIdx.x;                  // 0..233
  const int ch = bc & 1;
  const int lh = bc >> 1;                     // 0..116
  const int L = lh / F0N;
  const int h = lh - L * F0N;
  const float* W = (L == 0) ? w0 : ((L == 1) ? w1 : w2);
  const int fk = (L == 0) ? 39 : 64;
  const int tid = threadIdx.x;

  for (int e = tid; e < 4096; e += 256) {     // coalesced fp32 read
    int kc = e >> 7, s = e & 127;
    int k = ch * 32 + kc;
    T[kc * 132 + s] = (k < fk) ? W[(h * fk + k) * SN + s] : 0.0f;
  }
  __syncthreads();
  uint32_t* dst = (uint32_t*)(wt + (size_t)lh * WBLK);
  for (int i = tid; i < 2048; i += 256) {     // coalesced u32 writes, frag order
    int st = i >> 8, w = i & 255;
    int ln = w >> 2, jp = w & 3;
    int quad = ln >> 4, l16 = ln & 15;
    int k0 = quad * 8 + jp * 2;               // local k within this half
    int s = st * 16 + l16;
    dst[(size_t)(st * 2 + ch) * 256 + w] =
        (uint32_t)f2bf(T[k0 * 132 + s]) | ((uint32_t)f2bf(T[(k0 + 1) * 132 + s]) << 16);
  }
}

// ---------------- fused main kernel ----------------
// 256 blocks x 1024 threads (16 waves), 1 block/CU, 4 waves/SIMD.
// Block owns NB=8 batches x full s. Wave (st,bg): s-tile [st*16,st*16+16) x
// batches [bg*4,bg*4+4). Per layer: Bf register-cached; per h: 2 coalesced
// global W-frag loads (dist-1 register prefetch, no barriers in h-loop),
// 4 conflict-free scalar x0 ds_reads (dist-1 prefetch), 8 MFMA + 16 fmac.
// h runs to 40; h=39 has xs=0 (X0T pad) so its W (next layer's h0 / clamped)
// contributes 0; its prefetch seeds the next layer's h0.
// D-layout: D[s=st*16+quad*4+r][d=l16]; sum_d = shfl_xor over l16 bits.
__global__ __launch_bounds__(1024) void cin_main(
    const float* __restrict__ x,       // (2048, 39, 16) fp32
    const float* __restrict__ bias0, const float* __restrict__ bias1,
    const float* __restrict__ bias2,
    const uint16_t* __restrict__ wt,   // A-frag bf16 weights (d_ws)
    float* __restrict__ out) {         // (2048, 256) fp32

  __shared__ float    X0T[NB * 16 * X0TS];                // x0[b][d][h] f32, 23040 B
  __shared__ __align__(16) uint16_t XKT[NB * 16 * XKTS];  // xk[b][d][k] bf16, 18432 B

  const int tid  = threadIdx.x;
  const int lane = tid & 63;
  const int wave = tid >> 6;           // 0..15
  const int st   = wave >> 1;          // s-tile 0..7
  const int bg   = wave & 1;           // batch group 0..1
  const int l16  = lane & 15;          // = d (output col)
  const int quad = lane >> 4;
  const int bbase = blockIdx.x * NB;

  // zero X0T (h-pad 39..44 must be 0 -> xs=0 at h=39/40) and XKT (k-pad for L0)
  {
    float* p = X0T;                    // 5760 floats
#pragma unroll
    for (int i = 0; i < 6; i++) { int e = tid + 1024 * i; if (e < 5760) p[e] = 0.f; }
    uint32_t* q = (uint32_t*)XKT;      // 4608 dwords
#pragma unroll
    for (int i = 0; i < 5; i++) { int e = tid + 1024 * i; if (e < 4608) q[e] = 0u; }
  }
  __syncthreads();

  // fill X0T[b][d][h] = x[bbase+b][h][d]  (coalesced read, LDS transpose-scatter)
#pragma unroll
  for (int it = 0; it < 5; ++it) {
    int e = tid + it * 1024;           // e = (b*39 + h)*16 + d, total 4992
    if (e < NB * F0N * 16) {
      float v = x[(size_t)bbase * (F0N * 16) + e];
      int d = e & 15, p = e >> 4;
      int b = p / F0N, h = p - b * F0N;
      X0T[(b * 16 + d) * X0TS + h] = v;
    }
  }
  __syncthreads();

  // build layer-0 XKT[b][d][k] = bf16(x0[b][k][d]) for k<39, 0 for k in [39,64)
  if (tid < 512) {
    int b = tid >> 6, d = (tid >> 2) & 15, kg = tid & 3;
    const float* src = &X0T[(b * 16 + d) * X0TS];
    uint32_t* drow = (uint32_t*)&XKT[(b * 16 + d) * XKTS + kg * 16];
#pragma unroll
    for (int i2 = 0; i2 < 8; i2++) {
      int k0 = kg * 16 + i2 * 2;
      uint32_t lo = (k0 < 39)     ? (uint32_t)f2bf(src[k0])     : 0u;
      uint32_t hi = (k0 + 1 < 39) ? (uint32_t)f2bf(src[k0 + 1]) : 0u;
      drow[i2] = lo | (hi << 16);
    }
  }
  __syncthreads();   // XKT build visible for Bf loads

  // per-wave global W base (u16 units) — bg-pair waves share addresses (L1)
  const uint16_t* wlane = wt + st * 1024 + (size_t)lane * 8;
  int xrow[4];
#pragma unroll
  for (int bi = 0; bi < 4; ++bi) xrow[bi] = ((bg * 4 + bi) * 16 + l16) * X0TS;

  // seed prefetch: (L0, h0)
  short8 Wc0 = *(const short8*)(wlane);
  short8 Wc1 = *(const short8*)(wlane + 512);

#pragma unroll 1
  for (int L = 0; L < 3; ++L) {
    // register-cache B-fragments (h-invariant within layer); b = bg*4 + bi
    short8 Bf0[4], Bf1[4];
#pragma unroll
    for (int bi = 0; bi < 4; ++bi) {
      const uint16_t* r = XKT + ((bg * 4 + bi) * 16 + l16) * XKTS + quad * 8;
      Bf0[bi] = *(const short8*)r;          // k 0..31 chunk
      Bf1[bi] = *(const short8*)(r + 32);   // k 32..63 chunk
    }
    const float* bp = (L == 0) ? bias0 : ((L == 1) ? bias1 : bias2);
    float bvr[4];
#pragma unroll
    for (int r = 0; r < 4; ++r) bvr[r] = bp[st * 16 + quad * 4 + r];

    floatx4 z[4] = {};
    const floatx4 zero4 = {0.f, 0.f, 0.f, 0.f};

    // seed xs for h=0
    float xsC[4];
#pragma unroll
    for (int bi = 0; bi < 4; ++bi) xsC[bi] = X0T[xrow[bi]];

#pragma unroll 1
    for (int h = 0; h < 40; ++h) {
      // distance-1 prefetch of next h (or next layer's h0); wave-uniform addr
      short8 Wn0, Wn1;
      {
        int Ln = L, hh = h + 1;
        if (hh >= 39) { if (L < 2) { Ln = L + 1; hh = 0; } else hh = 38; }
        const uint16_t* wl = wlane + (size_t)(Ln * F0N + hh) * WBLK;
        Wn0 = *(const short8*)wl;
        Wn1 = *(const short8*)(wl + 512);
      }
      // dist-1 xs prefetch (h+1 <= 40 < X0TS, zero-padded)
      float xsN[4];
#pragma unroll
      for (int bi = 0; bi < 4; ++bi)
        xsN[bi] = X0T[xrow[bi] + h + 1];

#pragma unroll
      for (int bi = 0; bi < 4; ++bi) {
        floatx4 y = __builtin_amdgcn_mfma_f32_16x16x32_bf16(Wc0, Bf0[bi], zero4, 0, 0, 0);
        y = __builtin_amdgcn_mfma_f32_16x16x32_bf16(Wc1, Bf1[bi], y, 0, 0, 0);
#pragma unroll
        for (int r = 0; r < 4; ++r) z[bi][r] += xsC[bi] * y[r];
      }
      Wc0 = Wn0; Wc1 = Wn1;
#pragma unroll
      for (int bi = 0; bi < 4; ++bi) xsC[bi] = xsN[bi];
    }

    // ---- epilogue: bias+relu; xk handoff; sum_d (over l16) -> out ----
#pragma unroll
    for (int bi = 0; bi < 4; ++bi) {
      const int b = bg * 4 + bi;
#pragma unroll
      for (int r = 0; r < 4; ++r) {
        float t = fmaxf(z[bi][r] + bvr[r], 0.f);
        if (L < 2 && st < 4)               // xk = relu(z)[:, :64]; k = s < 64
          XKT[(b * 16 + l16) * XKTS + st * 16 + quad * 4 + r] = f2bf(t);
        float s4 = t;                       // reduce over d = l16 (bits 0..3)
        s4 += __shfl_xor(s4, 1);
        s4 += __shfl_xor(s4, 2);
        s4 += __shfl_xor(s4, 4);
        s4 += __shfl_xor(s4, 8);
        if (l16 == 0) {
          int s = st * 16 + quad * 4 + r;
          // concat: L0 s64:128 -> 0:64 ; L1 s64:128 -> 64:128 ; L2 s -> 128:256
          if (L == 2)       out[(size_t)(bbase + b) * 256 + 128 + s] = s4;
          else if (s >= 64) out[(size_t)(bbase + b) * 256 + L * 64 + (s - 64)] = s4;
        }
      }
    }
    if (L < 2) __syncthreads();   // handoff writes visible before next-layer Bf loads
  }
}

extern "C" void kernel_launch(void* const* d_in, const int* in_sizes, int n_in,
                              void* d_out, int out_size, void* d_ws, size_t ws_size,
                              hipStream_t stream) {
  (void)in_sizes; (void)n_in; (void)out_size; (void)ws_size;
  const float* x  = (const float*)d_in[0];
  const float* w0 = (const float*)d_in[1];
  const float* b0 = (const float*)d_in[2];
  const float* w1 = (const float*)d_in[3];
  const float* b1 = (const float*)d_in[4];
  const float* w2 = (const float*)d_in[5];
  const float* b2 = (const float*)d_in[6];
  uint16_t* wt    = (uint16_t*)d_ws;   // 117 * 8192 * 2 = 1,916,928 B

  cin_prepass<<<NHB2, 256, 0, stream>>>(w0, w1, w2, wt);
  cin_main<<<256, 1024, 0, stream>>>(x, b0, b1, b2, wt, (float*)d_out);
}